// Round 16
// baseline (159.524 us; speedup 1.0000x reference)
//
#include <hip/hip_runtime.h>

#define N_NODES 10000
#define NFEAT   512
#define NHID    256
#define NHID2   128
#define CAP     128   // max nnz/row stored; binomial(10000,0.005) mean 50, sd 7 -> 128 is >11 sigma

typedef __attribute__((ext_vector_type(8))) short bf16x8;
typedef __attribute__((ext_vector_type(4))) float f32x4;
typedef __attribute__((ext_vector_type(2))) int   i32x2;

__device__ __forceinline__ ushort f2bf(float f){
  union { float f; unsigned u; } v; v.f = f;
  unsigned r = v.u + 0x7FFFu + ((v.u >> 16) & 1u);   // round-to-nearest-even
  return (ushort)(r >> 16);
}
__device__ __forceinline__ float bf2f(ushort u){
  union { unsigned u; float f; } v; v.u = ((unsigned)u) << 16; return v.f;
}

// ---- K1: adj scan (blocks 0..9999, NT loads — isolated +8.7us win R12vsR15)
// + bf16 converts at the TAIL. pja writes are NT stores (one-shot stream;
// write-allocate into L2 during the scan is pure pollution). ----
__launch_bounds__(256)
__global__ void k_scan_cvt(const float* __restrict__ adj, const float* __restrict__ x,
                           const float* __restrict__ W1, const float* __restrict__ W2,
                           ushort* __restrict__ xb, ushort* __restrict__ w1t,
                           ushort* __restrict__ w2t, int* __restrict__ row_nnz,
                           i32x2* __restrict__ pja){
  const int b = blockIdx.x, t = threadIdx.x;

  if (b >= N_NODES){                    // ---- convert path (tail blocks) ----
    if (b < 15000){                     // x: 4 elems/thread, exact grid
      int i = ((b - N_NODES) * 256 + t) * 4;
      float4 q = *(const float4*)(x + i);
      ushort4 o; o.x = f2bf(q.x); o.y = f2bf(q.y); o.z = f2bf(q.z); o.w = f2bf(q.w);
      *(ushort4*)(xb + i) = o;
    } else if (b < 15512){              // W1t[n][k] = W1[k][n]
      int id = (b - 15000) * 256 + t;
      int n = id >> 9, k = id & 511;
      w1t[id] = f2bf(W1[k * NHID + n]);
    } else {                            // W2t[n][k] = W2[k][n]
      int id = (b - 15512) * 256 + t;
      int n = id >> 8, k = id & 255;
      w2t[id] = f2bf(W2[k * NHID2 + n]);
    }
    return;
  }

  // ---- scan path: row b, single nontemporal pass, register-cached ----
  const int r = b;
  const int lane = t & 63, w = t >> 6;
  const float* row = adj + (size_t)r * N_NODES;
  __shared__ int swave[4];

  f32x4 vals[10];
  #pragma unroll
  for (int v = 0; v < 9; v++)
    vals[v] = __builtin_nontemporal_load((const f32x4*)(row + v * 1024 + t * 4));
  vals[9] = (f32x4){0.f, 0.f, 0.f, 0.f};
  if (t < 196) vals[9] = __builtin_nontemporal_load((const f32x4*)(row + 9216 + t * 4));

  int cnt = 0;
  #pragma unroll
  for (int v = 0; v < 10; v++)
    cnt += (vals[v].x != 0.f) + (vals[v].y != 0.f) + (vals[v].z != 0.f) + (vals[v].w != 0.f);

  // wave shfl-scan + one cross-wave LDS step -> deterministic j-ascending order
  int incl = cnt;
  #pragma unroll
  for (int d = 1; d < 64; d <<= 1){
    int u = __shfl_up(incl, d, 64);
    if (lane >= d) incl += u;
  }
  if (lane == 63) swave[w] = incl;
  __syncthreads();
  int woff = 0, total = 0;
  #pragma unroll
  for (int i = 0; i < 4; i++){
    int s = swave[i];
    total += s;
    if (i < w) woff += s;
  }
  int pos = woff + incl - cnt;          // exclusive prefix

  #pragma unroll
  for (int v = 0; v < 10; v++){
    float q[4] = {vals[v].x, vals[v].y, vals[v].z, vals[v].w};
    #pragma unroll
    for (int e = 0; e < 4; e++){
      if (q[e] != 0.f && pos < CAP){
        __builtin_nontemporal_store((i32x2){(v * 1024 + t * 4 + e) << 8, __float_as_int(q[e])},
                                    pja + (size_t)r * CAP + pos);
        pos++;
      }
    }
  }
  if (t == 0) row_nnz[r] = min(total, CAP);
}

// ---- K2: gemm1 standalone — exact R12. XW1 = xb @ w1t^T, 64x64 tiles,
// column-split bf16 output (lo/hi 2.5MB, L2-resident for agg1). ----
__launch_bounds__(256)
__global__ void k_gemm1(const ushort* __restrict__ A, const ushort* __restrict__ Bt,
                        ushort* __restrict__ xw1_lo, ushort* __restrict__ xw1_hi){
  const int lane = threadIdx.x & 63;
  const int w    = threadIdx.x >> 6;
  const int wr   = w >> 1, wc = w & 1;
  const int r16  = lane & 15;
  const int kg   = lane >> 4;
  const int row0 = blockIdx.x * 64 + wr * 32;
  const int col0 = blockIdx.y * 64 + wc * 32;

  int arow[2], bcol[2];
  #pragma unroll
  for (int r = 0; r < 2; r++){
    int ar = row0 + r * 16 + r16;
    arow[r] = (ar >= N_NODES) ? (N_NODES - 1) : ar;
  }
  #pragma unroll
  for (int c = 0; c < 2; c++) bcol[c] = col0 + c * 16 + r16;

  f32x4 acc[2][2];
  #pragma unroll
  for (int r = 0; r < 2; r++)
    #pragma unroll
    for (int c = 0; c < 2; c++)
      acc[r][c] = (f32x4){0.f, 0.f, 0.f, 0.f};

  bf16x8 aA[2], bA[2], aB[2], bB[2];
  auto LOADF = [&](bf16x8* a, bf16x8* bb, int k0){
    #pragma unroll
    for (int r = 0; r < 2; r++)
      a[r] = *(const bf16x8*)(A + (size_t)arow[r] * NFEAT + k0 + kg * 8);
    #pragma unroll
    for (int c = 0; c < 2; c++)
      bb[c] = *(const bf16x8*)(Bt + (size_t)bcol[c] * NFEAT + k0 + kg * 8);
  };
  auto MM = [&](bf16x8* a, bf16x8* bb){
    #pragma unroll
    for (int r = 0; r < 2; r++)
      #pragma unroll
      for (int c = 0; c < 2; c++)
        acc[r][c] = __builtin_amdgcn_mfma_f32_16x16x32_bf16(a[r], bb[c], acc[r][c], 0, 0, 0);
  };

  LOADF(aA, bA, 0);
  #pragma unroll
  for (int k0 = 0; k0 < NFEAT; k0 += 64){
    if (k0 + 32 < NFEAT) LOADF(aB, bB, k0 + 32);
    MM(aA, bA);
    if (k0 + 64 < NFEAT) LOADF(aA, bA, k0 + 64);
    if (k0 + 32 < NFEAT) MM(aB, bB);
  }

  ushort* dst = (blockIdx.y < 2) ? xw1_lo : xw1_hi;
  const int cbase = (blockIdx.y < 2) ? 0 : 128;
  #pragma unroll
  for (int r = 0; r < 2; r++)
    #pragma unroll
    for (int c = 0; c < 2; c++){
      int col = col0 + c * 16 + r16 - cbase;
      #pragma unroll
      for (int i = 0; i < 4; i++){
        int row = row0 + r * 16 + kg * 4 + i;
        if (row < N_NODES) dst[(size_t)row * 128 + col] = f2bf(acc[r][c][i]);
      }
    }
}

// ---- K3: agg1 — R12 structure; pja staging loads are NT (read-once stream,
// keeps the 2.5MB gather table resident in each XCD's L2). ----
__launch_bounds__(256)
__global__ void k_agg1(const int* __restrict__ row_nnz, const i32x2* __restrict__ pja,
                       const ushort* __restrict__ xw1_lo, const ushort* __restrict__ xw1_hi,
                       const float* __restrict__ b1, ushort* __restrict__ Hb){
  const int half = blockIdx.x & 1;
  const int r0   = (blockIdx.x >> 1) * 16;
  const int t = threadIdx.x;
  __shared__ i32x2 sl[16][CAP];   // 16 KB
  __shared__ int   sn[16];
  if (t < 16) sn[t] = row_nnz[r0 + t];
  #pragma unroll
  for (int e = 0; e < 8; e++){
    int idx = t + e * 256;
    int rr = idx >> 7, kk = idx & (CAP - 1);
    sl[rr][kk] = __builtin_nontemporal_load(pja + (size_t)(r0 + rr) * CAP + kk);
  }
  __syncthreads();

  const int wv = t >> 6, lane = t & 63;
  const char* table = (const char*)(half ? xw1_hi : xw1_lo);
  const float bias0 = b1[half * 128 + lane * 2 + 0];
  const float bias1 = b1[half * 128 + lane * 2 + 1];

  #pragma unroll
  for (int rr = wv; rr < 16; rr += 4){
    const int n = sn[rr];
    float a0 = 0.f, a1 = 0.f;
    for (int k = 0; k < n; k++){
      i32x2 p = sl[rr][k];                 // LDS broadcast
      uint pk = *(const uint*)(table + p.x + lane * 4);   // 2 bf16 cols
      float a = __int_as_float(p.y);
      a0 += a * bf2f((ushort)(pk & 0xffff));
      a1 += a * bf2f((ushort)(pk >> 16));
    }
    uint o = ((uint)f2bf(fmaxf(a1 + bias1, 0.f)) << 16) | (uint)f2bf(fmaxf(a0 + bias0, 0.f));
    *(uint*)(Hb + (size_t)(r0 + rr) * NHID + half * 128 + lane * 2) = o;
  }
}

// ---- K4: gemm2 — exact R12. HW2b = Hb @ w2t^T (M=10000, K=256, N=128) ----
__launch_bounds__(256)
__global__ void k_gemm2(const ushort* __restrict__ A, const ushort* __restrict__ Bt,
                        ushort* __restrict__ C){
  const int lane = threadIdx.x & 63;
  const int w    = threadIdx.x >> 6;
  const int wr   = w >> 1, wc = w & 1;
  const int r16  = lane & 15;
  const int kg   = lane >> 4;
  const int row0 = blockIdx.x * 64 + wr * 32;
  const int col0 = blockIdx.y * 64 + wc * 32;

  int arow[2], bcol[2];
  #pragma unroll
  for (int r = 0; r < 2; r++){
    int ar = row0 + r * 16 + r16;
    arow[r] = (ar >= N_NODES) ? (N_NODES - 1) : ar;
  }
  #pragma unroll
  for (int c = 0; c < 2; c++) bcol[c] = col0 + c * 16 + r16;

  f32x4 acc[2][2];
  #pragma unroll
  for (int r = 0; r < 2; r++)
    #pragma unroll
    for (int c = 0; c < 2; c++)
      acc[r][c] = (f32x4){0.f, 0.f, 0.f, 0.f};

  bf16x8 aA[2], bA[2], aB[2], bB[2];
  auto LOADF = [&](bf16x8* a, bf16x8* bb, int k0){
    #pragma unroll
    for (int r = 0; r < 2; r++)
      a[r] = *(const bf16x8*)(A + (size_t)arow[r] * NHID + k0 + kg * 8);
    #pragma unroll
    for (int c = 0; c < 2; c++)
      bb[c] = *(const bf16x8*)(Bt + (size_t)bcol[c] * NHID + k0 + kg * 8);
  };
  auto MM = [&](bf16x8* a, bf16x8* bb){
    #pragma unroll
    for (int r = 0; r < 2; r++)
      #pragma unroll
      for (int c = 0; c < 2; c++)
        acc[r][c] = __builtin_amdgcn_mfma_f32_16x16x32_bf16(a[r], bb[c], acc[r][c], 0, 0, 0);
  };

  LOADF(aA, bA, 0);
  #pragma unroll
  for (int k0 = 0; k0 < NHID; k0 += 64){
    if (k0 + 32 < NHID) LOADF(aB, bB, k0 + 32);
    MM(aA, bA);
    if (k0 + 64 < NHID) LOADF(aA, bA, k0 + 64);
    if (k0 + 32 < NHID) MM(aB, bB);
  }

  #pragma unroll
  for (int r = 0; r < 2; r++)
    #pragma unroll
    for (int c = 0; c < 2; c++){
      int col = col0 + c * 16 + r16;
      #pragma unroll
      for (int i = 0; i < 4; i++){
        int row = row0 + r * 16 + kg * 4 + i;
        if (row < N_NODES) C[(size_t)row * NHID2 + col] = f2bf(acc[r][c][i]);
      }
    }
}

// ---- K5: agg2 — R12 structure; pja staging loads NT. ----
__launch_bounds__(256)
__global__ void k_agg2(const int* __restrict__ row_nnz, const i32x2* __restrict__ pja,
                       const ushort* __restrict__ hw2b, const float* __restrict__ b2,
                       float* __restrict__ out){
  const int r0 = blockIdx.x * 8;
  const int t = threadIdx.x;
  __shared__ i32x2 sl[8][CAP];    // 8 KB
  __shared__ int   sn[8];
  if (t < 8) sn[t] = row_nnz[r0 + t];
  #pragma unroll
  for (int e = 0; e < 4; e++){
    int idx = t + e * 256;
    int rr = idx >> 7, kk = idx & (CAP - 1);
    sl[rr][kk] = __builtin_nontemporal_load(pja + (size_t)(r0 + rr) * CAP + kk);
  }
  __syncthreads();

  const int wv = t >> 6, lane = t & 63;
  const char* table = (const char*)hw2b;
  const float bias0 = b2[lane * 2 + 0];
  const float bias1 = b2[lane * 2 + 1];

  #pragma unroll
  for (int rr = wv; rr < 8; rr += 4){
    const int n = sn[rr];
    float a0 = 0.f, a1 = 0.f;
    for (int k = 0; k < n; k++){
      i32x2 p = sl[rr][k];
      uint pk = *(const uint*)(table + p.x + lane * 4);
      float a = __int_as_float(p.y);
      a0 += a * bf2f((ushort)(pk & 0xffff));
      a1 += a * bf2f((ushort)(pk >> 16));
    }
    float2 o = make_float2(fmaxf(a0 + bias0, 0.f), fmaxf(a1 + bias1, 0.f));
    *(float2*)(out + (size_t)(r0 + rr) * NHID2 + lane * 2) = o;
  }
}

extern "C" void kernel_launch(void* const* d_in, const int* in_sizes, int n_in,
                              void* d_out, int out_size, void* d_ws, size_t ws_size,
                              hipStream_t stream){
  const float* x   = (const float*)d_in[0];
  const float* adj = (const float*)d_in[1];
  const float* W1  = (const float*)d_in[2];
  const float* b1  = (const float*)d_in[3];
  const float* W2  = (const float*)d_in[4];
  const float* b2  = (const float*)d_in[5];
  float* out = (float*)d_out;
  char*  ws  = (char*)d_ws;

  // workspace layout (16B-aligned), total ~33.6 MB
  ushort* xb     = (ushort*)(ws);              // x bf16:      10,240,000
  ushort* w1t    = (ushort*)(ws + 10240000);   // W1t bf16:       262,144
  ushort* w2t    = (ushort*)(ws + 10502144);   // W2t bf16:        65,536
  ushort* xw1_lo = (ushort*)(ws + 10567680);   // XW1 lo bf16:  2,560,000 (L2-resident)
  ushort* xw1_hi = (ushort*)(ws + 13127680);   // XW1 hi bf16:  2,560,000 (L2-resident)
  ushort* Hb     = (ushort*)(ws + 15687680);   // H bf16:       5,120,000
  ushort* hw2b   = (ushort*)(ws + 20807680);   // HW2 bf16:     2,560,000 (L2-resident)
  int*    nnz    = (int*)(ws + 23367680);      // 40,000
  i32x2*  pja    = (i32x2*)(ws + 23407680);    // packed (j<<8, a): 10,240,000

  // K1: adj scan (NT loads, NT pja stores) + converts at the tail
  k_scan_cvt<<<15640, 256, 0, stream>>>(adj, x, W1, W2, xb, w1t, w2t, nnz, pja);

  // K2: gemm1 standalone (628 blocks, bf16 operands)
  k_gemm1<<<dim3(157, 4), 256, 0, stream>>>(xb, w1t, xw1_lo, xw1_hi);

  // K3: layer-1 aggregate (wave-per-row-half, NT pja staging)
  k_agg1<<<1250, 256, 0, stream>>>(nnz, pja, xw1_lo, xw1_hi, b1, Hb);

  // K4: HW2b = Hb @ W2 (64x64 tiles, 314 blocks)
  k_gemm2<<<dim3(157, 2), 256, 0, stream>>>(Hb, w2t, hw2b);

  // K5: layer-2 aggregate (NT pja staging)
  k_agg2<<<1250, 256, 0, stream>>>(nnz, pja, hw2b, b2, out);
}

// Round 17
// 141.841 us; speedup vs baseline: 1.1247x; 1.1247x over previous
//
#include <hip/hip_runtime.h>

#define N_NODES 10000
#define NFEAT   512
#define NHID    256
#define NHID2   128
#define CAP     128   // max nnz/row stored; binomial(10000,0.005) mean 50, sd 7 -> 128 is >11 sigma

typedef __attribute__((ext_vector_type(8))) short bf16x8;
typedef __attribute__((ext_vector_type(4))) float f32x4;
typedef __attribute__((ext_vector_type(2))) int   i32x2;

__device__ __forceinline__ ushort f2bf(float f){
  union { float f; unsigned u; } v; v.f = f;
  unsigned r = v.u + 0x7FFFu + ((v.u >> 16) & 1u);   // round-to-nearest-even
  return (ushort)(r >> 16);
}
__device__ __forceinline__ float bf2f(ushort u){
  union { unsigned u; float f; } v; v.u = ((unsigned)u) << 16; return v.f;
}

// ---- K1: adj scan (blocks 0..9999, NT loads) + bf16 converts at the TAIL.
// Measured standalone 78.1us (R5). NT adj loads: isolated +8.7us win (R12 vs
// R15). pja stores CACHED (R16: NT pja stores cost +17us — pja is read twice). ----
__launch_bounds__(256)
__global__ void k_scan_cvt(const float* __restrict__ adj, const float* __restrict__ x,
                           const float* __restrict__ W1, const float* __restrict__ W2,
                           ushort* __restrict__ xb, ushort* __restrict__ w1t,
                           ushort* __restrict__ w2t, int* __restrict__ row_nnz,
                           i32x2* __restrict__ pja){
  const int b = blockIdx.x, t = threadIdx.x;

  if (b >= N_NODES){                    // ---- convert path (tail blocks) ----
    if (b < 15000){                     // x: 4 elems/thread, exact grid
      int i = ((b - N_NODES) * 256 + t) * 4;
      float4 q = *(const float4*)(x + i);
      ushort4 o; o.x = f2bf(q.x); o.y = f2bf(q.y); o.z = f2bf(q.z); o.w = f2bf(q.w);
      *(ushort4*)(xb + i) = o;
    } else if (b < 15512){              // W1t[n][k] = W1[k][n]
      int id = (b - 15000) * 256 + t;
      int n = id >> 9, k = id & 511;
      w1t[id] = f2bf(W1[k * NHID + n]);
    } else {                            // W2t[n][k] = W2[k][n]
      int id = (b - 15512) * 256 + t;
      int n = id >> 8, k = id & 255;
      w2t[id] = f2bf(W2[k * NHID2 + n]);
    }
    return;
  }

  // ---- scan path: row b, single nontemporal pass, register-cached ----
  const int r = b;
  const int lane = t & 63, w = t >> 6;
  const float* row = adj + (size_t)r * N_NODES;
  __shared__ int swave[4];

  f32x4 vals[10];
  #pragma unroll
  for (int v = 0; v < 9; v++)
    vals[v] = __builtin_nontemporal_load((const f32x4*)(row + v * 1024 + t * 4));
  vals[9] = (f32x4){0.f, 0.f, 0.f, 0.f};
  if (t < 196) vals[9] = __builtin_nontemporal_load((const f32x4*)(row + 9216 + t * 4));

  int cnt = 0;
  #pragma unroll
  for (int v = 0; v < 10; v++)
    cnt += (vals[v].x != 0.f) + (vals[v].y != 0.f) + (vals[v].z != 0.f) + (vals[v].w != 0.f);

  // wave shfl-scan + one cross-wave LDS step -> deterministic j-ascending order
  int incl = cnt;
  #pragma unroll
  for (int d = 1; d < 64; d <<= 1){
    int u = __shfl_up(incl, d, 64);
    if (lane >= d) incl += u;
  }
  if (lane == 63) swave[w] = incl;
  __syncthreads();
  int woff = 0, total = 0;
  #pragma unroll
  for (int i = 0; i < 4; i++){
    int s = swave[i];
    total += s;
    if (i < w) woff += s;
  }
  int pos = woff + incl - cnt;          // exclusive prefix

  #pragma unroll
  for (int v = 0; v < 10; v++){
    float q[4] = {vals[v].x, vals[v].y, vals[v].z, vals[v].w};
    #pragma unroll
    for (int e = 0; e < 4; e++){
      if (q[e] != 0.f && pos < CAP){
        pja[(size_t)r * CAP + pos] = (i32x2){(v * 1024 + t * 4 + e) << 8, __float_as_int(q[e])};
        pos++;
      }
    }
  }
  if (t == 0) row_nnz[r] = min(total, CAP);
}

// ---- K2: gemm1 standalone: XW1 = xb @ w1t^T (M=10000, K=512), 64x64 tiles,
// double-buffered fragments. Column-split bf16 output (lo/hi 2.5MB, L2-resident). ----
__launch_bounds__(256)
__global__ void k_gemm1(const ushort* __restrict__ A, const ushort* __restrict__ Bt,
                        ushort* __restrict__ xw1_lo, ushort* __restrict__ xw1_hi){
  const int lane = threadIdx.x & 63;
  const int w    = threadIdx.x >> 6;
  const int wr   = w >> 1, wc = w & 1;
  const int r16  = lane & 15;
  const int kg   = lane >> 4;
  const int row0 = blockIdx.x * 64 + wr * 32;
  const int col0 = blockIdx.y * 64 + wc * 32;

  int arow[2], bcol[2];
  #pragma unroll
  for (int r = 0; r < 2; r++){
    int ar = row0 + r * 16 + r16;
    arow[r] = (ar >= N_NODES) ? (N_NODES - 1) : ar;
  }
  #pragma unroll
  for (int c = 0; c < 2; c++) bcol[c] = col0 + c * 16 + r16;

  f32x4 acc[2][2];
  #pragma unroll
  for (int r = 0; r < 2; r++)
    #pragma unroll
    for (int c = 0; c < 2; c++)
      acc[r][c] = (f32x4){0.f, 0.f, 0.f, 0.f};

  bf16x8 aA[2], bA[2], aB[2], bB[2];
  auto LOADF = [&](bf16x8* a, bf16x8* bb, int k0){
    #pragma unroll
    for (int r = 0; r < 2; r++)
      a[r] = *(const bf16x8*)(A + (size_t)arow[r] * NFEAT + k0 + kg * 8);
    #pragma unroll
    for (int c = 0; c < 2; c++)
      bb[c] = *(const bf16x8*)(Bt + (size_t)bcol[c] * NFEAT + k0 + kg * 8);
  };
  auto MM = [&](bf16x8* a, bf16x8* bb){
    #pragma unroll
    for (int r = 0; r < 2; r++)
      #pragma unroll
      for (int c = 0; c < 2; c++)
        acc[r][c] = __builtin_amdgcn_mfma_f32_16x16x32_bf16(a[r], bb[c], acc[r][c], 0, 0, 0);
  };

  LOADF(aA, bA, 0);
  #pragma unroll
  for (int k0 = 0; k0 < NFEAT; k0 += 64){
    if (k0 + 32 < NFEAT) LOADF(aB, bB, k0 + 32);
    MM(aA, bA);
    if (k0 + 64 < NFEAT) LOADF(aA, bA, k0 + 64);
    if (k0 + 32 < NFEAT) MM(aB, bB);
  }

  ushort* dst = (blockIdx.y < 2) ? xw1_lo : xw1_hi;
  const int cbase = (blockIdx.y < 2) ? 0 : 128;
  #pragma unroll
  for (int r = 0; r < 2; r++)
    #pragma unroll
    for (int c = 0; c < 2; c++){
      int col = col0 + c * 16 + r16 - cbase;
      #pragma unroll
      for (int i = 0; i < 4; i++){
        int row = row0 + r * 16 + kg * 4 + i;
        if (row < N_NODES) dst[(size_t)row * 128 + col] = f2bf(acc[r][c][i]);
      }
    }
}

// ---- K3: agg1 — one WAVE per row-half; 1250 blocks; half=bid&1 picks the
// L2-resident 2.5MB table; 16 rows/block; wave handles 4 row-halves. ----
__launch_bounds__(256)
__global__ void k_agg1(const int* __restrict__ row_nnz, const i32x2* __restrict__ pja,
                       const ushort* __restrict__ xw1_lo, const ushort* __restrict__ xw1_hi,
                       const float* __restrict__ b1, ushort* __restrict__ Hb){
  const int half = blockIdx.x & 1;
  const int r0   = (blockIdx.x >> 1) * 16;
  const int t = threadIdx.x;
  __shared__ i32x2 sl[16][CAP];   // 16 KB
  __shared__ int   sn[16];
  if (t < 16) sn[t] = row_nnz[r0 + t];
  #pragma unroll
  for (int e = 0; e < 8; e++){
    int idx = t + e * 256;
    int rr = idx >> 7, kk = idx & (CAP - 1);
    sl[rr][kk] = pja[(size_t)(r0 + rr) * CAP + kk];
  }
  __syncthreads();

  const int wv = t >> 6, lane = t & 63;
  const char* table = (const char*)(half ? xw1_hi : xw1_lo);
  const float bias0 = b1[half * 128 + lane * 2 + 0];
  const float bias1 = b1[half * 128 + lane * 2 + 1];

  #pragma unroll
  for (int rr = wv; rr < 16; rr += 4){
    const int n = sn[rr];
    float a0 = 0.f, a1 = 0.f;
    for (int k = 0; k < n; k++){
      i32x2 p = sl[rr][k];                 // LDS broadcast
      uint pk = *(const uint*)(table + p.x + lane * 4);   // 2 bf16 cols
      float a = __int_as_float(p.y);
      a0 += a * bf2f((ushort)(pk & 0xffff));
      a1 += a * bf2f((ushort)(pk >> 16));
    }
    uint o = ((uint)f2bf(fmaxf(a1 + bias1, 0.f)) << 16) | (uint)f2bf(fmaxf(a0 + bias0, 0.f));
    *(uint*)(Hb + (size_t)(r0 + rr) * NHID + half * 128 + lane * 2) = o;
  }
}

// ---- K4: gemm2: HW2b = Hb @ w2t^T (M=10000, K=256, N=128), 64x64 tiles ----
__launch_bounds__(256)
__global__ void k_gemm2(const ushort* __restrict__ A, const ushort* __restrict__ Bt,
                        ushort* __restrict__ C){
  const int lane = threadIdx.x & 63;
  const int w    = threadIdx.x >> 6;
  const int wr   = w >> 1, wc = w & 1;
  const int r16  = lane & 15;
  const int kg   = lane >> 4;
  const int row0 = blockIdx.x * 64 + wr * 32;
  const int col0 = blockIdx.y * 64 + wc * 32;

  int arow[2], bcol[2];
  #pragma unroll
  for (int r = 0; r < 2; r++){
    int ar = row0 + r * 16 + r16;
    arow[r] = (ar >= N_NODES) ? (N_NODES - 1) : ar;
  }
  #pragma unroll
  for (int c = 0; c < 2; c++) bcol[c] = col0 + c * 16 + r16;

  f32x4 acc[2][2];
  #pragma unroll
  for (int r = 0; r < 2; r++)
    #pragma unroll
    for (int c = 0; c < 2; c++)
      acc[r][c] = (f32x4){0.f, 0.f, 0.f, 0.f};

  bf16x8 aA[2], bA[2], aB[2], bB[2];
  auto LOADF = [&](bf16x8* a, bf16x8* bb, int k0){
    #pragma unroll
    for (int r = 0; r < 2; r++)
      a[r] = *(const bf16x8*)(A + (size_t)arow[r] * NHID + k0 + kg * 8);
    #pragma unroll
    for (int c = 0; c < 2; c++)
      bb[c] = *(const bf16x8*)(Bt + (size_t)bcol[c] * NHID + k0 + kg * 8);
  };
  auto MM = [&](bf16x8* a, bf16x8* bb){
    #pragma unroll
    for (int r = 0; r < 2; r++)
      #pragma unroll
      for (int c = 0; c < 2; c++)
        acc[r][c] = __builtin_amdgcn_mfma_f32_16x16x32_bf16(a[r], bb[c], acc[r][c], 0, 0, 0);
  };

  LOADF(aA, bA, 0);
  #pragma unroll
  for (int k0 = 0; k0 < NHID; k0 += 64){
    if (k0 + 32 < NHID) LOADF(aB, bB, k0 + 32);
    MM(aA, bA);
    if (k0 + 64 < NHID) LOADF(aA, bA, k0 + 64);
    if (k0 + 32 < NHID) MM(aB, bB);
  }

  #pragma unroll
  for (int r = 0; r < 2; r++)
    #pragma unroll
    for (int c = 0; c < 2; c++){
      int col = col0 + c * 16 + r16;
      #pragma unroll
      for (int i = 0; i < 4; i++){
        int row = row0 + r * 16 + kg * 4 + i;
        if (row < N_NODES) C[(size_t)row * NHID2 + col] = f2bf(acc[r][c][i]);
      }
    }
}

// ---- K5: agg2 — one wave per row; hw2b 2.5MB L2-resident ----
__launch_bounds__(256)
__global__ void k_agg2(const int* __restrict__ row_nnz, const i32x2* __restrict__ pja,
                       const ushort* __restrict__ hw2b, const float* __restrict__ b2,
                       float* __restrict__ out){
  const int r0 = blockIdx.x * 8;
  const int t = threadIdx.x;
  __shared__ i32x2 sl[8][CAP];    // 8 KB
  __shared__ int   sn[8];
  if (t < 8) sn[t] = row_nnz[r0 + t];
  #pragma unroll
  for (int e = 0; e < 4; e++){
    int idx = t + e * 256;
    int rr = idx >> 7, kk = idx & (CAP - 1);
    sl[rr][kk] = pja[(size_t)(r0 + rr) * CAP + kk];
  }
  __syncthreads();

  const int wv = t >> 6, lane = t & 63;
  const char* table = (const char*)hw2b;
  const float bias0 = b2[lane * 2 + 0];
  const float bias1 = b2[lane * 2 + 1];

  #pragma unroll
  for (int rr = wv; rr < 8; rr += 4){
    const int n = sn[rr];
    float a0 = 0.f, a1 = 0.f;
    for (int k = 0; k < n; k++){
      i32x2 p = sl[rr][k];
      uint pk = *(const uint*)(table + p.x + lane * 4);
      float a = __int_as_float(p.y);
      a0 += a * bf2f((ushort)(pk & 0xffff));
      a1 += a * bf2f((ushort)(pk >> 16));
    }
    float2 o = make_float2(fmaxf(a0 + bias0, 0.f), fmaxf(a1 + bias1, 0.f));
    *(float2*)(out + (size_t)(r0 + rr) * NHID2 + lane * 2) = o;
  }
}

extern "C" void kernel_launch(void* const* d_in, const int* in_sizes, int n_in,
                              void* d_out, int out_size, void* d_ws, size_t ws_size,
                              hipStream_t stream){
  const float* x   = (const float*)d_in[0];
  const float* adj = (const float*)d_in[1];
  const float* W1  = (const float*)d_in[2];
  const float* b1  = (const float*)d_in[3];
  const float* W2  = (const float*)d_in[4];
  const float* b2  = (const float*)d_in[5];
  float* out = (float*)d_out;
  char*  ws  = (char*)d_ws;

  // workspace layout (16B-aligned), total ~33.6 MB
  ushort* xb     = (ushort*)(ws);              // x bf16:      10,240,000
  ushort* w1t    = (ushort*)(ws + 10240000);   // W1t bf16:       262,144
  ushort* w2t    = (ushort*)(ws + 10502144);   // W2t bf16:        65,536
  ushort* xw1_lo = (ushort*)(ws + 10567680);   // XW1 lo bf16:  2,560,000 (L2-resident)
  ushort* xw1_hi = (ushort*)(ws + 13127680);   // XW1 hi bf16:  2,560,000 (L2-resident)
  ushort* Hb     = (ushort*)(ws + 15687680);   // H bf16:       5,120,000
  ushort* hw2b   = (ushort*)(ws + 20807680);   // HW2 bf16:     2,560,000 (L2-resident)
  int*    nnz    = (int*)(ws + 23367680);      // 40,000
  i32x2*  pja    = (i32x2*)(ws + 23407680);    // packed (j<<8, a): 10,240,000

  // K1: adj scan (10000 blocks, NT loads) + converts at the tail — 78.1us (R5)
  k_scan_cvt<<<15640, 256, 0, stream>>>(adj, x, W1, W2, xb, w1t, w2t, nnz, pja);

  // K2: gemm1 standalone (628 blocks, bf16 operands)
  k_gemm1<<<dim3(157, 4), 256, 0, stream>>>(xb, w1t, xw1_lo, xw1_hi);

  // K3: layer-1 aggregate (wave-per-row-half)
  k_agg1<<<1250, 256, 0, stream>>>(nnz, pja, xw1_lo, xw1_hi, b1, Hb);

  // K4: HW2b = Hb @ W2 (64x64 tiles, 314 blocks)
  k_gemm2<<<dim3(157, 2), 256, 0, stream>>>(Hb, w2t, hw2b);

  // K5: layer-2 aggregate
  k_agg2<<<1250, 256, 0, stream>>>(nnz, pja, hw2b, b2, out);
}